// Round 8
// baseline (258.761 us; speedup 1.0000x reference)
//
#include <hip/hip_runtime.h>
#include <math.h>

// Problem constants (B=4, S=4096, D=2048, E=64, K=2)
#define BS_TOT 16384
#define DDIM   2048
#define NEXP   64
#define TOPK   2

#define NKC    4                 // split-K chunks
#define KC     (DDIM / NKC)      // 512 k per chunk
#define NTL    (KC / 32)         // 16 k-tiles per wave

typedef _Float16 half8   __attribute__((ext_vector_type(8)));
typedef float    floatx4 __attribute__((ext_vector_type(4)));

// ---------------------------------------------------------------------------
// Pre-pass (layout proven R4-R7): W [D][E] fp32 -> fragment-major hi/lo fp16
// (lo scaled 2048). halfs index: t*4096 + f*1024 + h*512 + lane*8 + j,
//   element = {hi,lo}( W[k = t*32 + (lane>>4)*8 + j][e = f*16 + (lane&15)] )
// 512 KB in d_ws, L2-resident for the GEMM.
// ---------------------------------------------------------------------------
__global__ __launch_bounds__(64)
void wsplit_kernel(const float* __restrict__ W, _Float16* __restrict__ wint)
{
    const int b = blockIdx.x;            // 0..255 : t = b>>2, f = b&3
    const int t = b >> 2, f = b & 3;
    const int lane = threadIdx.x;        // one wave
    const int rr = lane & 15, kg = lane >> 4;
    half8 vh, vl;
#pragma unroll
    for (int j = 0; j < 8; ++j) {
        const float v = W[(size_t)(t * 32 + kg * 8 + j) * NEXP + f * 16 + rr];
        const _Float16 h = (_Float16)v;
        vh[j] = h;
        vl[j] = (_Float16)((v - (float)h) * 2048.0f);
    }
    *(half8*)(wint + (size_t)t * 4096 + f * 1024 +       lane * 8) = vh;
    *(half8*)(wint + (size_t)t * 4096 + f * 1024 + 512 + lane * 8) = vl;
}

// ---------------------------------------------------------------------------
// GEMM, TLP-robust form: 4096 blocks x 256 thr = 16384 INDEPENDENT waves.
// No LDS, no barriers, no software pipeline to collapse. Wave (mB,kc,wv):
// 16 rows x 16 experts (et = wv) x 512 k. Per 32-k tile: 2 A loads (float4,
// shared by the block's 4 waves -> L1), 2 B loads (contiguous 16B from the
// L2-resident fragment-major wint), in-reg fp32->f16 hi/lo cvt, 3 MFMA
// (hi*hi -> acc; lo*hi + hi*lo -> accl). acc = 8 VGPR; per-wave state tiny,
// so occupancy (not ILP) hides latency: even 1 load in flight per wave
// gives ~4-8 MB machine-wide in flight => BW-bound, not latency-bound.
// Deposit: plain coalesced stores to private split-K slab (no atomics).
// Frag maps (HW-proven R1-R7): A row=lane&15, k=(lane>>4)*8+j; B col=lane&15;
// D col=lane&15 (expert), row=(lane>>4)*4+reg (x-row).
// ---------------------------------------------------------------------------
__global__ __launch_bounds__(256, 4)
void gemm_kernel(const float* __restrict__ x, const _Float16* __restrict__ wint,
                 float* __restrict__ lpart)
{
    const int tid  = threadIdx.x;
    const int lane = tid & 63;
    const int wv   = tid >> 6;           // expert quarter 0..3
    const int mB   = blockIdx.x >> 2;    // 0..1023 (16-row tile)
    const int kc   = blockIdx.x & 3;     // 0..3 (512-k chunk)
    const int rr   = lane & 15, kg = lane >> 4;

    const float*    xq = x + (size_t)(mB * 16 + rr) * DDIM + kc * KC + kg * 8;
    const _Float16* wq = wint + (size_t)(kc * NTL) * 4096 + wv * 1024 + lane * 8;

    floatx4 a[2][2];                     // 1-tile-ahead A ping-pong
    a[0][0] = *(const floatx4*)(xq);
    a[0][1] = *(const floatx4*)(xq + 4);

    floatx4 acc  = (floatx4){0.f, 0.f, 0.f, 0.f};
    floatx4 accl = (floatx4){0.f, 0.f, 0.f, 0.f};

#pragma unroll
    for (int t = 0; t < NTL; ++t) {
        // B tile t: two contiguous 16B/lane loads (1 KB each, L2-resident)
        const half8 bh = *(const half8*)(wq + t * 4096);
        const half8 bl = *(const half8*)(wq + t * 4096 + 512);
        // A tile t+1 in flight while we convert/compute tile t
        if (t + 1 < NTL) {
            a[(t + 1) & 1][0] = *(const floatx4*)(xq + (t + 1) * 32);
            a[(t + 1) & 1][1] = *(const floatx4*)(xq + (t + 1) * 32 + 4);
        }
        half8 ah, al;
#pragma unroll
        for (int i = 0; i < 4; ++i) {
            _Float16 h; float v;
            v = a[t & 1][0][i]; h = (_Float16)v; ah[i]     = h; al[i]     = (_Float16)((v - (float)h) * 2048.0f);
            v = a[t & 1][1][i]; h = (_Float16)v; ah[4 + i] = h; al[4 + i] = (_Float16)((v - (float)h) * 2048.0f);
        }
        acc  = __builtin_amdgcn_mfma_f32_16x16x32_f16(ah, bh, acc,  0, 0, 0);
        accl = __builtin_amdgcn_mfma_f32_16x16x32_f16(al, bh, accl, 0, 0, 0);
        accl = __builtin_amdgcn_mfma_f32_16x16x32_f16(ah, bl, accl, 0, 0, 0);
    }

    // ---- deposit split-K partial: row = mB*16 + kg*4 + r, e = wv*16 + rr
    const float inv = 1.0f / 2048.0f;
    float* lp = lpart + (size_t)kc * ((size_t)BS_TOT * NEXP)
              + (size_t)(mB * 16 + kg * 4) * NEXP + wv * 16 + rr;
#pragma unroll
    for (int r = 0; r < 4; ++r)
        lp[(size_t)r * NEXP] = acc[r] + accl[r] * inv;
}

// ---------------------------------------------------------------------------
// Epilogue: 512 blocks x 256 thr; each wave handles 8 rows. Sums the 4
// split-K partials (coalesced 256B-per-wave loads), adds bias + noise,
// proven softmax/top-2 (verbatim logic from all passing rounds).
// ---------------------------------------------------------------------------
__global__ __launch_bounds__(256)
void epilogue_kernel(const float* __restrict__ lpart, const float* __restrict__ bias,
                     const float* __restrict__ noise, float* __restrict__ out)
{
    const int tid  = threadIdx.x;
    const int lane = tid & 63;
    const int wv   = tid >> 6;
    const int row0 = blockIdx.x * 32;

    float* const scores_out = out + 2 * BS_TOT * TOPK;
    float* const iout       = out + BS_TOT * TOPK;
    const float blane = bias[lane];

#pragma unroll
    for (int j = 0; j < 8; ++j) {
        const int r2 = row0 + wv * 8 + j;
        float v = 0.0f;
#pragma unroll
        for (int p = 0; p < NKC; ++p)
            v += lpart[(size_t)p * ((size_t)BS_TOT * NEXP) + (size_t)r2 * NEXP + lane];
        v += blane + 0.1f * noise[(size_t)r2 * NEXP + lane];

        float m = v;
#pragma unroll
        for (int off = 1; off < 64; off <<= 1) m = fmaxf(m, __shfl_xor(m, off));
        const float p = __expf(v - m);
        float s = p;
#pragma unroll
        for (int off = 1; off < 64; off <<= 1) s += __shfl_xor(s, off);
        const float sc = p * (1.0f / s);

        scores_out[(size_t)r2 * NEXP + lane] = sc;   // 256B coalesced

        // top-2 across 64 lanes on logits (order-identical to scores),
        // ties -> lower index (matches jax.lax.top_k).
        float a1 = v, a2 = -INFINITY;
        int   i1 = lane, i2 = 0x7fffffff;
#pragma unroll
        for (int off = 1; off < 64; off <<= 1) {
            const float o1 = __shfl_xor(a1, off), o2 = __shfl_xor(a2, off);
            const int  oi1 = __shfl_xor(i1, off), oi2 = __shfl_xor(i2, off);
            if (o1 > a1 || (o1 == a1 && oi1 < i1)) {
                if (a1 > o2 || (a1 == o2 && i1 < oi2)) { a2 = a1; i2 = i1; }
                else                                   { a2 = o2; i2 = oi2; }
                a1 = o1; i1 = oi1;
            } else {
                if (o1 > a2 || (o1 == a2 && oi1 < i2)) { a2 = o1; i2 = oi1; }
            }
        }
        const float s1 = __shfl(sc, i1);   // bitwise == scores entries
        const float s2 = __shfl(sc, i2);
        if (lane == 0) {
            out[(size_t)r2 * TOPK + 0]  = s1;
            out[(size_t)r2 * TOPK + 1]  = s2;
            iout[(size_t)r2 * TOPK + 0] = (float)i1;
            iout[(size_t)r2 * TOPK + 1] = (float)i2;
        }
    }
}

extern "C" void kernel_launch(void* const* d_in, const int* in_sizes, int n_in,
                              void* d_out, int out_size, void* d_ws, size_t ws_size,
                              hipStream_t stream)
{
    const float* x     = (const float*)d_in[0];
    const float* W     = (const float*)d_in[1];
    const float* bias  = (const float*)d_in[2];
    const float* noise = (const float*)d_in[3];
    float* out = (float*)d_out;
    (void)in_sizes; (void)n_in; (void)out_size; (void)ws_size;

    _Float16* wint = (_Float16*)d_ws;                       // 512 KB hi/lo W^T
    float* lpart   = (float*)((char*)d_ws + (1 << 20));     // 16 MB split-K partials

    hipLaunchKernelGGL(wsplit_kernel, dim3(256), dim3(64), 0, stream, W, wint);
    hipLaunchKernelGGL(gemm_kernel, dim3((BS_TOT / 16) * NKC), dim3(256), 0,
                       stream, x, wint, lpart);
    hipLaunchKernelGGL(epilogue_kernel, dim3(BS_TOT / 32), dim3(256), 0, stream,
                       lpart, bias, noise, out);
}